// Round 21
// baseline (139.675 us; speedup 1.0000x reference)
//
#include <hip/hip_runtime.h>
#include <math.h>

// ---------------------------------------------------------------------------
// Problem: B=64 batches. a_p = a@W1^T + b1 [64,1024]; b_p = b@W2^T + b2.
// cost[b,i,j] = (a_p[b,i]-b_p[b,j])^2 ; DTW DP R[i,j]=cost+min(diag,up,left);
// out[b] = R[1023,1023].
// ---------------------------------------------------------------------------

#define L 1024
#define BATCH 64

// ---------------- GEMM: out[b,i] = sum_k X[b,k]*W[i,k] (+ bias) ------------
__global__ __launch_bounds__(256) void proj_kernel(
    const float* __restrict__ a, const float* __restrict__ b,
    const float* __restrict__ W1, const float* __restrict__ b1,
    const float* __restrict__ W2, const float* __restrict__ b2,
    float* __restrict__ ap, float* __restrict__ bp, int KC) {
  int part = blockIdx.x >> 7;
  int sub = blockIdx.x & 127;
  const float* X;
  const float* W;
  const float* bias;
  float* out;
  int i0;
  if (sub < 64) {
    X = a; W = W1; bias = b1; out = ap + part * BATCH * L; i0 = sub * 16;
  } else {
    X = b; W = W2; bias = b2; out = bp + part * BATCH * L; i0 = (sub - 64) * 16;
  }

  __shared__ float a_s[64][36];
  __shared__ float w_s[16][36];

  int tid = threadIdx.x;
  int lane_b = tid & 63;
  int iq = tid >> 6;

  float acc[4] = {0.f, 0.f, 0.f, 0.f};

  int kbeg = part * KC;
  int kend = kbeg + KC;
  for (int k0 = kbeg; k0 < kend; k0 += 32) {
    {
      int row = tid >> 2;
      int kl = (tid & 3) * 8;
      const float4* src = reinterpret_cast<const float4*>(&X[row * L + k0 + kl]);
      float4 v0 = src[0];
      float4 v1 = src[1];
      *reinterpret_cast<float4*>(&a_s[row][kl]) = v0;
      *reinterpret_cast<float4*>(&a_s[row][kl + 4]) = v1;
    }
    {
      int row = tid >> 4;
      int kl = (tid & 15) * 2;
      float2 v = *reinterpret_cast<const float2*>(&W[(i0 + row) * L + k0 + kl]);
      w_s[row][kl] = v.x;
      w_s[row][kl + 1] = v.y;
    }
    __syncthreads();
    #pragma unroll
    for (int kl = 0; kl < 32; kl += 4) {
      float4 av = *reinterpret_cast<const float4*>(&a_s[lane_b][kl]);
      #pragma unroll
      for (int m = 0; m < 4; ++m) {
        float4 wv = *reinterpret_cast<const float4*>(&w_s[iq * 4 + m][kl]);
        acc[m] += av.x * wv.x + av.y * wv.y + av.z * wv.z + av.w * wv.w;
      }
    }
    __syncthreads();
  }

  #pragma unroll
  for (int m = 0; m < 4; ++m) {
    int i = i0 + iq * 4 + m;
    float bv = (part == 0) ? bias[i] : 0.f;
    out[lane_b * L + i] = acc[m] + bv;
  }
}

// ---------------- DTW: anti-diagonal wavefront, 8 waves x CPL=2 ------------
// 512 threads = 8 waves. Global lane g = w*64+t owns columns {2g, 2g+1}.
// All 64 lanes of wave w jointly compute anti-diagonal d = s - 31*w at step
// s. Cell (i=d-j, j): up = p1[m] (diag d-1, same col), left = p1[m-1]
// (diag d-1, col-1), diag = p2[m-1] (diag d-2, col-1). Cells independent ->
// per-step critical path ~ min3+fma (R20 proved the form: 99 cyc/step at
// CPL=4). CPL=2 halves per-wave instrs (~14/step) and 8 waves = 2/SIMD so
// co-resident waves' streams interleave to fill hazard slots (R19: 1.52x).
// Trims vs R20: p2m1 = PREVIOUS step's p1m1 (register carry — no sh2 DPP,
// no cndmask, no feedprev); p2_1 is dead at CPL=2 (only p2_0 carried);
// R[0,0]'s diag seed 0 comes via p2m1c init (no in-loop fixups at all).
// ap transport: A0 = ap[d-2g], A1 = ap[d-2g-1] in-lane window; A1 <- old
// A0 (rename), A0 <- DPP from lane t-1's old A1 (= ap[d-2g] exactly);
// lane 0 fed from per-group-loaded walking apchunk. INF skirts in ap_pad
// make out-of-range cells INF (no predicates; no NaN: INF-x squared = INF).
// Ring (per adjacent wave pair) carries lane-63 boundary x1 (col 128w-1...
// i.e. col 2*64w-1) per diag, slot = diag & 63. Production at step
// d + 31w; consumption by wave w+1 at step d+1+31(w+1) -> gap 32 steps =
// exactly one barrier-ordered group (OFF=31); group read slots and write
// slots are disjoint 32-slot halves mod 64; slot reuse distance 2 groups.
// Ring pre-INF'd; ramp values are INF (vprod starts INF) — never garbage.
// Result: R[1023,1023] = x1 of (w=7,t=63) at d=2046 -> s=2263 = group 70,
// k=23.

#define NW 8
#define CPL 2
#define KBAR 32
#define OFF 31
#define NG 71                        // 2272 steps; last useful step 2263
#define APOFF 1248                   // covers min index -(159*7 + 127 + 1)
#define APPAD 3560                   // APOFF + 63 + 2240 + pad

__device__ __forceinline__ float dpp_shr1_z(float v) {
  // wave_shr:1, bound_ctrl=1: lane i <- lane i-1; lane 0 <- 0. One instr.
  int r = __builtin_amdgcn_update_dpp(0, __float_as_int(v), 0x138, 0xf, 0xf,
                                      true);
  return __int_as_float(r);
}

__device__ __forceinline__ float dpp_shl1_z(float v) {
  // wave_shl:1, bound_ctrl=1: lane i <- lane i+1; lane 63 <- 0. One instr.
  int r = __builtin_amdgcn_update_dpp(0, __float_as_int(v), 0x130, 0xf, 0xf,
                                      true);
  return __int_as_float(r);
}

__device__ __forceinline__ float min3f(float x, float y, float z) {
  float r;
  asm("v_min3_f32 %0, %1, %2, %3" : "=v"(r) : "v"(x), "v"(y), "v"(z));
  return r;
}

__global__ __launch_bounds__(512, 1) void dtw_kernel(
    const float* __restrict__ app, const float* __restrict__ bpp,
    float* __restrict__ out, int parts) {
  const int b = blockIdx.x;
  const int tid = threadIdx.x;
  const int w = tid >> 6;
  const int t = tid & 63;
  const int woff = OFF * w;
  const float INF = INFINITY;

  __shared__ float ap_pad[APPAD];
  __shared__ float ring[NW - 1][64];

  // ap_pad[APOFF + i] = sum_p ap_part[p][b,i]; INF skirts.
  for (int idx = tid; idx < APPAD; idx += 512) {
    int src = idx - APOFF;
    float v = INF;
    if ((unsigned)src < (unsigned)L) {
      v = app[b * L + src];
      for (int p = 1; p < parts; ++p) v += app[p * BATCH * L + b * L + src];
    }
    ap_pad[idx] = v;
  }
  if (tid < (NW - 1) * 64) reinterpret_cast<float*>(ring)[tid] = INF;

  const int colb = tid * CPL;  // tid == g; columns 2g, 2g+1
  float2 bv = *reinterpret_cast<const float2*>(&bpp[b * L + colb]);
  for (int p = 1; p < parts; ++p) {
    float2 u = *reinterpret_cast<const float2*>(
        &bpp[p * BATCH * L + b * L + colb]);
    bv.x += u.x; bv.y += u.y;
  }
  const float bpv0 = bv.x, bpv1 = bv.y;

  float p1_0 = INF, p1_1 = INF;   // diag d-1, cols 2g, 2g+1
  float p2_0 = INF;               // diag d-2, col 2g
  float p2m1c = (w == 0 && t == 0) ? 0.f : INF;  // diag d-2, col 2g-1 (carry)
  float A0 = INF, A1 = INF;       // ap[d-2g], ap[d-2g-1]
  float ringchunk = INF, vprod = INF, apchunk;
  float res = 0.f;
  const bool lane0 = (t == 0);
  const bool lane63 = (t == 63);
  // A0(lane t, step s) = ap[s - 159w - 2t]; chunk lane t = index s0 + t.
  const int apbase = APOFF - (128 + OFF) * w;

  __syncthreads();

#define DTW_GROUP(s0v, LASTG)                                                \
  {                                                                          \
    const int s0 = (s0v);                                                    \
    apchunk = ap_pad[apbase + s0 + t - 2 * 0];                               \
    if (w == 0)                                                              \
      ringchunk = INF;                                                       \
    else if (t < KBAR)                                                       \
      ringchunk = ring[w - 1][(s0 + t - woff - 1) & 63];                     \
    _Pragma("unroll")                                                        \
    for (int k = 0; k < KBAR; ++k) {                                         \
      float sh1 = dpp_shr1_z(p1_1);                                          \
      float p1m1 = lane0 ? ringchunk : sh1;                                  \
      ringchunk = dpp_shl1_z(ringchunk);                                     \
      float sha = dpp_shr1_z(A1);                                            \
      A1 = A0;                                                               \
      A0 = lane0 ? apchunk : sha;                                            \
      apchunk = dpp_shl1_z(apchunk);                                         \
      float d0 = A0 - bpv0, d1 = A1 - bpv1;                                  \
      float b0 = min3f(p1_0, p1m1, p2m1c);                                   \
      float b1 = min3f(p1_1, p1_0, p2_0);                                    \
      float x0 = __builtin_fmaf(d0, d0, b0);                                 \
      float x1 = __builtin_fmaf(d1, d1, b1);                                 \
      p2m1c = p1m1;                                                          \
      p2_0 = p1_0;                                                           \
      p1_0 = x0;                                                             \
      p1_1 = x1;                                                             \
      vprod = dpp_shl1_z(vprod);                                             \
      vprod = lane63 ? x1 : vprod;                                           \
      if ((LASTG) && k == 23) res = x1;                                      \
    }                                                                        \
    if (w < NW - 1 && t >= 64 - KBAR)                                        \
      ring[w][(s0 + t - 32 - woff) & 63] = vprod;                            \
    __syncthreads();                                                         \
  }

  for (int g = 0; g < NG - 1; ++g) DTW_GROUP(g * KBAR, false);
  DTW_GROUP((NG - 1) * KBAR, true);
#undef DTW_GROUP

  if (w == NW - 1 && t == 63) out[b] = res;  // R[1023,1023]
}

extern "C" void kernel_launch(void* const* d_in, const int* in_sizes, int n_in,
                              void* d_out, int out_size, void* d_ws, size_t ws_size,
                              hipStream_t stream) {
  const float* a  = (const float*)d_in[0];
  const float* b  = (const float*)d_in[1];
  const float* W1 = (const float*)d_in[2];
  const float* b1 = (const float*)d_in[3];
  const float* W2 = (const float*)d_in[4];
  const float* b2 = (const float*)d_in[5];
  float* out = (float*)d_out;

  size_t per_part = (size_t)2 * BATCH * L * sizeof(float);
  int parts = 1;
  if (ws_size >= 4 * per_part) parts = 4;
  else if (ws_size >= 2 * per_part) parts = 2;

  float* ap = (float*)d_ws;                    // parts x [BATCH, L]
  float* bp = ap + (size_t)parts * BATCH * L;  // parts x [BATCH, L]

  proj_kernel<<<128 * parts, 256, 0, stream>>>(a, b, W1, b1, W2, b2,
                                               ap, bp, L / parts);
  dtw_kernel<<<BATCH, 512, 0, stream>>>(ap, bp, out, parts);
}

// Round 22
// 106.303 us; speedup vs baseline: 1.3139x; 1.3139x over previous
//
#include <hip/hip_runtime.h>
#include <math.h>

// ---------------------------------------------------------------------------
// Problem: B=64 batches. a_p = a@W1^T + b1 [64,1024]; b_p = b@W2^T + b2.
// cost[b,i,j] = (a_p[b,i]-b_p[b,j])^2 ; DTW DP R[i,j]=cost+min(diag,up,left);
// out[b] = R[1023,1023].
// ---------------------------------------------------------------------------

#define L 1024
#define BATCH 64

// ---------------- GEMM: out[b,i] = sum_k X[b,k]*W[i,k] (+ bias) ------------
__global__ __launch_bounds__(256) void proj_kernel(
    const float* __restrict__ a, const float* __restrict__ b,
    const float* __restrict__ W1, const float* __restrict__ b1,
    const float* __restrict__ W2, const float* __restrict__ b2,
    float* __restrict__ ap, float* __restrict__ bp, int KC) {
  int part = blockIdx.x >> 7;
  int sub = blockIdx.x & 127;
  const float* X;
  const float* W;
  const float* bias;
  float* out;
  int i0;
  if (sub < 64) {
    X = a; W = W1; bias = b1; out = ap + part * BATCH * L; i0 = sub * 16;
  } else {
    X = b; W = W2; bias = b2; out = bp + part * BATCH * L; i0 = (sub - 64) * 16;
  }

  __shared__ float a_s[64][36];
  __shared__ float w_s[16][36];

  int tid = threadIdx.x;
  int lane_b = tid & 63;
  int iq = tid >> 6;

  float acc[4] = {0.f, 0.f, 0.f, 0.f};

  int kbeg = part * KC;
  int kend = kbeg + KC;
  for (int k0 = kbeg; k0 < kend; k0 += 32) {
    {
      int row = tid >> 2;
      int kl = (tid & 3) * 8;
      const float4* src = reinterpret_cast<const float4*>(&X[row * L + k0 + kl]);
      float4 v0 = src[0];
      float4 v1 = src[1];
      *reinterpret_cast<float4*>(&a_s[row][kl]) = v0;
      *reinterpret_cast<float4*>(&a_s[row][kl + 4]) = v1;
    }
    {
      int row = tid >> 4;
      int kl = (tid & 15) * 2;
      float2 v = *reinterpret_cast<const float2*>(&W[(i0 + row) * L + k0 + kl]);
      w_s[row][kl] = v.x;
      w_s[row][kl + 1] = v.y;
    }
    __syncthreads();
    #pragma unroll
    for (int kl = 0; kl < 32; kl += 4) {
      float4 av = *reinterpret_cast<const float4*>(&a_s[lane_b][kl]);
      #pragma unroll
      for (int m = 0; m < 4; ++m) {
        float4 wv = *reinterpret_cast<const float4*>(&w_s[iq * 4 + m][kl]);
        acc[m] += av.x * wv.x + av.y * wv.y + av.z * wv.z + av.w * wv.w;
      }
    }
    __syncthreads();
  }

  #pragma unroll
  for (int m = 0; m < 4; ++m) {
    int i = i0 + iq * 4 + m;
    float bv = (part == 0) ? bias[i] : 0.f;
    out[lane_b * L + i] = acc[m] + bv;
  }
}

// ---------------- DTW: anti-diagonal wavefront, explicit reg rotation ------
// Geometry = R20 (passed, absmax 0): global lane g=w*64+t owns columns
// [4g,4g+4); wave w computes anti-diagonal d = s - 31*w at step s; cells in
// a step are MUTUALLY INDEPENDENT (critical path = min3+fma). INF skirts in
// ap_pad make out-of-range cells INF -> no predicates. Ring slot math,
// OFF=31 (production exactly one barrier-ordered group before consumption,
// disjoint 32-slot halves), seeds: all R20-verbatim.
// NEW vs R20: the ~11 per-step register-rename movs (A3=A2..., p2=p1,
// p1=x, feedprev) are eliminated STRUCTURALLY:
//  - p ping-pong: sets sA/sB alternate diag d-1 / d-2 roles each step; the
//    new diag overwrites the dying set (2-step cycle, zero movs).
//  - A-window rotation: 4 named regs; incoming value overwrites the dead
//    oldest; roles rotate (r3,r0,r1,r2) per step (4-step cycle, zero movs).
//  - p2m1 carry: p2m1 = previous step's p1m1 (pure SSA rename; kills the
//    sh2 DPP + cndmask + feedprev of R20).
// Inner loop = 8 x 4 unrolled micro-steps (32%4==0 -> same roles at every
// group boundary). Per-step: 5 DPP-class + 3 cndmask + 4 sub + 4 min3 +
// 4 fma = 20 instrs, independent-cell dataflow.
// Result: R[1023,1023] = x3 of (w=3,t=63) at d=2046 -> s=2139 = group 66,
// k=27 (LASTG-guarded capture, compile-time).

#define NW 4
#define CPL 4
#define KBAR 32
#define OFF 31
#define NG 67                        // groups 0..66; 2144 steps total
#define APOFF 864
#define APPAD 3048

__device__ __forceinline__ float dpp_shr1_z(float v) {
  // wave_shr:1, bound_ctrl=1: lane i <- lane i-1; lane 0 <- 0. One instr.
  int r = __builtin_amdgcn_update_dpp(0, __float_as_int(v), 0x138, 0xf, 0xf,
                                      true);
  return __int_as_float(r);
}

__device__ __forceinline__ float dpp_shl1_z(float v) {
  // wave_shl:1, bound_ctrl=1: lane i <- lane i+1; lane 63 <- 0. One instr.
  int r = __builtin_amdgcn_update_dpp(0, __float_as_int(v), 0x130, 0xf, 0xf,
                                      true);
  return __int_as_float(r);
}

__device__ __forceinline__ float min3f(float x, float y, float z) {
  float r;
  asm("v_min3_f32 %0, %1, %2, %3" : "=v"(r) : "v"(x), "v"(y), "v"(z));
  return r;
}

__global__ __launch_bounds__(256, 1) void dtw_kernel(
    const float* __restrict__ app, const float* __restrict__ bpp,
    float* __restrict__ out, int parts) {
  const int b = blockIdx.x;
  const int tid = threadIdx.x;
  const int w = tid >> 6;
  const int t = tid & 63;
  const int woff = OFF * w;
  const float INF = INFINITY;

  __shared__ float ap_pad[APPAD];
  __shared__ float ring[NW - 1][64];

  // ap_pad[APOFF + i] = sum_p ap_part[p][b,i]; INF skirts.
  for (int idx = tid; idx < APPAD; idx += 256) {
    int src = idx - APOFF;
    float v = INF;
    if ((unsigned)src < (unsigned)L) {
      v = app[b * L + src];
      for (int p = 1; p < parts; ++p) v += app[p * BATCH * L + b * L + src];
    }
    ap_pad[idx] = v;
  }
  if (tid < (NW - 1) * 64) reinterpret_cast<float*>(ring)[tid] = INF;

  const int colb = tid * CPL;  // tid == g (global lane)
  float4 bv = *reinterpret_cast<const float4*>(&bpp[b * L + colb]);
  for (int p = 1; p < parts; ++p) {
    float4 u = *reinterpret_cast<const float4*>(
        &bpp[p * BATCH * L + b * L + colb]);
    bv.x += u.x; bv.y += u.y; bv.z += u.z; bv.w += u.w;
  }
  const float bpv0 = bv.x, bpv1 = bv.y, bpv2 = bv.z, bpv3 = bv.w;

  // Ping-pong diag sets and rotating A-window (explicit registers).
  float sA0 = INF, sA1 = INF, sA2 = INF, sA3 = INF;  // diag d-1 at step 0
  float sB0 = INF, sB1 = INF, sB2 = INF, sB3 = INF;  // diag d-2 at step 0
  float r0 = INF, r1 = INF, r2 = INF, r3 = INF;      // A-window
  float p2m1 = (w == 0 && t == 0) ? 0.f : INF;       // diag d-2, col-1 carry
  float ringchunk = INF, vprod = INF, apchunk;
  float res = 0.f;
  const bool lane0 = (t == 0);
  const bool lane63 = (t == 63);
  const int apbase = APOFF + t - (256 + OFF) * w;

  __syncthreads();

  // One micro-step. P* = diag d-1 (read), Q* = diag d-2 (Q0..Q2 read; all
  // four overwritten with the new diag d). a_0..a_3 = previous A-window;
  // a_3 (oldest, dead) receives the incoming value and becomes current A0.
#define MICRO(P0, P1, P2, P3, Q0, Q1, Q2, Q3, a_0, a_1, a_2, a_3, KK, LASTG) \
  {                                                                          \
    float sh1 = dpp_shr1_z(P3);                                              \
    float p1m1 = lane0 ? ringchunk : sh1;                                    \
    ringchunk = dpp_shl1_z(ringchunk);                                       \
    float sha = dpp_shr1_z(a_3);                                             \
    a_3 = lane0 ? apchunk : sha;       /* a_3 = current A0 = ap[d-4g] */     \
    apchunk = dpp_shl1_z(apchunk);                                           \
    float d0 = a_3 - bpv0, d1 = a_0 - bpv1;                                  \
    float d2 = a_1 - bpv2, d3 = a_2 - bpv3;                                  \
    float b0 = min3f(P0, p1m1, p2m1);                                        \
    float b1 = min3f(P1, P0, Q0);                                            \
    float b2 = min3f(P2, P1, Q1);                                            \
    float b3 = min3f(P3, P2, Q2);                                            \
    Q0 = __builtin_fmaf(d0, d0, b0);                                         \
    Q1 = __builtin_fmaf(d1, d1, b1);                                         \
    Q2 = __builtin_fmaf(d2, d2, b2);                                         \
    Q3 = __builtin_fmaf(d3, d3, b3);                                         \
    p2m1 = p1m1;                                                             \
    vprod = dpp_shl1_z(vprod);                                               \
    vprod = lane63 ? Q3 : vprod;                                             \
    if ((LASTG) && (KK) == 27) res = Q3;                                     \
  }

#define DTW_GROUP(s0v, LASTG)                                                \
  {                                                                          \
    const int s0 = (s0v);                                                    \
    apchunk = ap_pad[apbase + s0];                                           \
    if (w == 0)                                                              \
      ringchunk = INF;                                                       \
    else if (t < KBAR)                                                       \
      ringchunk = ring[w - 1][(s0 + t - woff - 1) & 63];                     \
    _Pragma("unroll")                                                        \
    for (int kk = 0; kk < KBAR; kk += 4) {                                   \
      MICRO(sA0, sA1, sA2, sA3, sB0, sB1, sB2, sB3,                          \
            r0, r1, r2, r3, kk + 0, LASTG);                                  \
      MICRO(sB0, sB1, sB2, sB3, sA0, sA1, sA2, sA3,                          \
            r3, r0, r1, r2, kk + 1, LASTG);                                  \
      MICRO(sA0, sA1, sA2, sA3, sB0, sB1, sB2, sB3,                          \
            r2, r3, r0, r1, kk + 2, LASTG);                                  \
      MICRO(sB0, sB1, sB2, sB3, sA0, sA1, sA2, sA3,                          \
            r1, r2, r3, r0, kk + 3, LASTG);                                  \
    }                                                                        \
    if (w < NW - 1 && t >= 64 - KBAR)                                        \
      ring[w][(s0 + t - 32 - woff) & 63] = vprod;                            \
    __syncthreads();                                                         \
  }

  for (int g = 0; g < NG - 1; ++g) DTW_GROUP(g * KBAR, false);
  DTW_GROUP((NG - 1) * KBAR, true);
#undef DTW_GROUP
#undef MICRO

  if (w == NW - 1 && t == 63) out[b] = res;  // R[1023,1023]
}

extern "C" void kernel_launch(void* const* d_in, const int* in_sizes, int n_in,
                              void* d_out, int out_size, void* d_ws, size_t ws_size,
                              hipStream_t stream) {
  const float* a  = (const float*)d_in[0];
  const float* b  = (const float*)d_in[1];
  const float* W1 = (const float*)d_in[2];
  const float* b1 = (const float*)d_in[3];
  const float* W2 = (const float*)d_in[4];
  const float* b2 = (const float*)d_in[5];
  float* out = (float*)d_out;

  size_t per_part = (size_t)2 * BATCH * L * sizeof(float);
  int parts = 1;
  if (ws_size >= 4 * per_part) parts = 4;
  else if (ws_size >= 2 * per_part) parts = 2;

  float* ap = (float*)d_ws;                    // parts x [BATCH, L]
  float* bp = ap + (size_t)parts * BATCH * L;  // parts x [BATCH, L]

  proj_kernel<<<128 * parts, 256, 0, stream>>>(a, b, W1, b1, W2, b2,
                                               ap, bp, L / parts);
  dtw_kernel<<<BATCH, 256, 0, stream>>>(ap, bp, out, parts);
}

// Round 23
// 106.195 us; speedup vs baseline: 1.3153x; 1.0010x over previous
//
#include <hip/hip_runtime.h>
#include <math.h>

// ---------------------------------------------------------------------------
// Problem: B=64 batches. a_p = a@W1^T + b1 [64,1024]; b_p = b@W2^T + b2.
// cost[b,i,j] = (a_p[b,i]-b_p[b,j])^2 ; DTW DP R[i,j]=cost+min(diag,up,left);
// out[b] = R[1023,1023].
// ---------------------------------------------------------------------------

#define L 1024
#define BATCH 64

// ---------------- GEMM: out[b,i] = sum_k X[b,k]*W[i,k] (+ bias) ------------
__global__ __launch_bounds__(256) void proj_kernel(
    const float* __restrict__ a, const float* __restrict__ b,
    const float* __restrict__ W1, const float* __restrict__ b1,
    const float* __restrict__ W2, const float* __restrict__ b2,
    float* __restrict__ ap, float* __restrict__ bp, int KC) {
  int part = blockIdx.x >> 7;
  int sub = blockIdx.x & 127;
  const float* X;
  const float* W;
  const float* bias;
  float* out;
  int i0;
  if (sub < 64) {
    X = a; W = W1; bias = b1; out = ap + part * BATCH * L; i0 = sub * 16;
  } else {
    X = b; W = W2; bias = b2; out = bp + part * BATCH * L; i0 = (sub - 64) * 16;
  }

  __shared__ float a_s[64][36];
  __shared__ float w_s[16][36];

  int tid = threadIdx.x;
  int lane_b = tid & 63;
  int iq = tid >> 6;

  float acc[4] = {0.f, 0.f, 0.f, 0.f};

  int kbeg = part * KC;
  int kend = kbeg + KC;
  for (int k0 = kbeg; k0 < kend; k0 += 32) {
    {
      int row = tid >> 2;
      int kl = (tid & 3) * 8;
      const float4* src = reinterpret_cast<const float4*>(&X[row * L + k0 + kl]);
      float4 v0 = src[0];
      float4 v1 = src[1];
      *reinterpret_cast<float4*>(&a_s[row][kl]) = v0;
      *reinterpret_cast<float4*>(&a_s[row][kl + 4]) = v1;
    }
    {
      int row = tid >> 4;
      int kl = (tid & 15) * 2;
      float2 v = *reinterpret_cast<const float2*>(&W[(i0 + row) * L + k0 + kl]);
      w_s[row][kl] = v.x;
      w_s[row][kl + 1] = v.y;
    }
    __syncthreads();
    #pragma unroll
    for (int kl = 0; kl < 32; kl += 4) {
      float4 av = *reinterpret_cast<const float4*>(&a_s[lane_b][kl]);
      #pragma unroll
      for (int m = 0; m < 4; ++m) {
        float4 wv = *reinterpret_cast<const float4*>(&w_s[iq * 4 + m][kl]);
        acc[m] += av.x * wv.x + av.y * wv.y + av.z * wv.z + av.w * wv.w;
      }
    }
    __syncthreads();
  }

  #pragma unroll
  for (int m = 0; m < 4; ++m) {
    int i = i0 + iq * 4 + m;
    float bv = (part == 0) ? bias[i] : 0.f;
    out[lane_b * L + i] = acc[m] + bv;
  }
}

// ---------------- DTW: anti-diagonal wavefront, single-instr mov_dpp -------
// Geometry/dataflow = R22 (passed, absmax 0): global lane g=w*64+t owns
// columns [4g,4g+4); wave w computes anti-diagonal d = s - 31*w at step s;
// cells in a step are MUTUALLY INDEPENDENT. INF skirts -> no predicates.
// Ring: OFF=31, production exactly one barrier-ordered group before
// consumption, disjoint 32-slot halves, reuse distance 2 groups.
// NEW vs R22: all DPP transports use __builtin_amdgcn_mov_dpp (NO old
// operand) instead of update_dpp(0, ...). update_dpp's tied old operand
// forces a v_mov dst,0 before EVERY v_mov_b32_dpp — R22's counters show
// ~37 emitted VALU instrs/step vs ~20 ideal (VALUBusy 74% of active CUs x
// 100 cyc/step), and 5 DPPs/step x (mov + hazard) is the prime suspect.
// mov_dpp lowers to exactly one v_mov_b32_dpp.
// Register rotation (ping-pong sA/sB, rotating r0..r3, p2m1 carry) kept
// from R22. Result: R[1023,1023] = Q3 of (w=3,t=63) at step 2139 = group
// 66, k=27.

#define NW 4
#define CPL 4
#define KBAR 32
#define OFF 31
#define NG 67                        // groups 0..66; 2144 steps total
#define APOFF 864
#define APPAD 3048

#if __has_builtin(__builtin_amdgcn_mov_dpp)
#define DPP_MOV(v, ctrl) __builtin_amdgcn_mov_dpp((v), (ctrl), 0xf, 0xf, true)
#else
#define DPP_MOV(v, ctrl) \
  __builtin_amdgcn_update_dpp(0, (v), (ctrl), 0xf, 0xf, true)
#endif

__device__ __forceinline__ float dpp_shr1_z(float v) {
  // wave_shr:1, bound_ctrl=1: lane i <- lane i-1; lane 0 <- 0.
  return __int_as_float(DPP_MOV(__float_as_int(v), 0x138));
}

__device__ __forceinline__ float dpp_shl1_z(float v) {
  // wave_shl:1, bound_ctrl=1: lane i <- lane i+1; lane 63 <- 0.
  return __int_as_float(DPP_MOV(__float_as_int(v), 0x130));
}

__device__ __forceinline__ float min3f(float x, float y, float z) {
  float r;
  asm("v_min3_f32 %0, %1, %2, %3" : "=v"(r) : "v"(x), "v"(y), "v"(z));
  return r;
}

__global__ __launch_bounds__(256, 1) void dtw_kernel(
    const float* __restrict__ app, const float* __restrict__ bpp,
    float* __restrict__ out, int parts) {
  const int b = blockIdx.x;
  const int tid = threadIdx.x;
  const int w = tid >> 6;
  const int t = tid & 63;
  const int woff = OFF * w;
  const float INF = INFINITY;

  __shared__ float ap_pad[APPAD];
  __shared__ float ring[NW - 1][64];

  // ap_pad[APOFF + i] = sum_p ap_part[p][b,i]; INF skirts.
  for (int idx = tid; idx < APPAD; idx += 256) {
    int src = idx - APOFF;
    float v = INF;
    if ((unsigned)src < (unsigned)L) {
      v = app[b * L + src];
      for (int p = 1; p < parts; ++p) v += app[p * BATCH * L + b * L + src];
    }
    ap_pad[idx] = v;
  }
  if (tid < (NW - 1) * 64) reinterpret_cast<float*>(ring)[tid] = INF;

  const int colb = tid * CPL;  // tid == g (global lane)
  float4 bv = *reinterpret_cast<const float4*>(&bpp[b * L + colb]);
  for (int p = 1; p < parts; ++p) {
    float4 u = *reinterpret_cast<const float4*>(
        &bpp[p * BATCH * L + b * L + colb]);
    bv.x += u.x; bv.y += u.y; bv.z += u.z; bv.w += u.w;
  }
  const float bpv0 = bv.x, bpv1 = bv.y, bpv2 = bv.z, bpv3 = bv.w;

  // Ping-pong diag sets and rotating A-window (explicit registers).
  float sA0 = INF, sA1 = INF, sA2 = INF, sA3 = INF;  // diag d-1 at step 0
  float sB0 = INF, sB1 = INF, sB2 = INF, sB3 = INF;  // diag d-2 at step 0
  float r0 = INF, r1 = INF, r2 = INF, r3 = INF;      // A-window
  float p2m1 = (w == 0 && t == 0) ? 0.f : INF;       // diag d-2, col-1 carry
  float ringchunk = INF, vprod = INF, apchunk;
  float res = 0.f;
  const bool lane0 = (t == 0);
  const bool lane63 = (t == 63);
  const int apbase = APOFF + t - (256 + OFF) * w;

  __syncthreads();

  // One micro-step. P* = diag d-1 (read), Q* = diag d-2 (Q0..Q2 read; all
  // four overwritten with the new diag d). a_0..a_3 = previous A-window;
  // a_3 (oldest, dead) receives the incoming value and becomes current A0.
#define MICRO(P0, P1, P2, P3, Q0, Q1, Q2, Q3, a_0, a_1, a_2, a_3, KK, LASTG) \
  {                                                                          \
    float sh1 = dpp_shr1_z(P3);                                              \
    float p1m1 = lane0 ? ringchunk : sh1;                                    \
    ringchunk = dpp_shl1_z(ringchunk);                                       \
    float sha = dpp_shr1_z(a_3);                                             \
    a_3 = lane0 ? apchunk : sha;       /* a_3 = current A0 = ap[d-4g] */     \
    apchunk = dpp_shl1_z(apchunk);                                           \
    float d0 = a_3 - bpv0, d1 = a_0 - bpv1;                                  \
    float d2 = a_1 - bpv2, d3 = a_2 - bpv3;                                  \
    float b0 = min3f(P0, p1m1, p2m1);                                        \
    float b1 = min3f(P1, P0, Q0);                                            \
    float b2 = min3f(P2, P1, Q1);                                            \
    float b3 = min3f(P3, P2, Q2);                                            \
    Q0 = __builtin_fmaf(d0, d0, b0);                                         \
    Q1 = __builtin_fmaf(d1, d1, b1);                                         \
    Q2 = __builtin_fmaf(d2, d2, b2);                                         \
    Q3 = __builtin_fmaf(d3, d3, b3);                                         \
    p2m1 = p1m1;                                                             \
    vprod = dpp_shl1_z(vprod);                                               \
    vprod = lane63 ? Q3 : vprod;                                             \
    if ((LASTG) && (KK) == 27) res = Q3;                                     \
  }

#define DTW_GROUP(s0v, LASTG)                                                \
  {                                                                          \
    const int s0 = (s0v);                                                    \
    apchunk = ap_pad[apbase + s0];                                           \
    if (w == 0)                                                              \
      ringchunk = INF;                                                       \
    else if (t < KBAR)                                                       \
      ringchunk = ring[w - 1][(s0 + t - woff - 1) & 63];                     \
    _Pragma("unroll")                                                        \
    for (int kk = 0; kk < KBAR; kk += 4) {                                   \
      MICRO(sA0, sA1, sA2, sA3, sB0, sB1, sB2, sB3,                          \
            r0, r1, r2, r3, kk + 0, LASTG);                                  \
      MICRO(sB0, sB1, sB2, sB3, sA0, sA1, sA2, sA3,                          \
            r3, r0, r1, r2, kk + 1, LASTG);                                  \
      MICRO(sA0, sA1, sA2, sA3, sB0, sB1, sB2, sB3,                          \
            r2, r3, r0, r1, kk + 2, LASTG);                                  \
      MICRO(sB0, sB1, sB2, sB3, sA0, sA1, sA2, sA3,                          \
            r1, r2, r3, r0, kk + 3, LASTG);                                  \
    }                                                                        \
    if (w < NW - 1 && t >= 64 - KBAR)                                        \
      ring[w][(s0 + t - 32 - woff) & 63] = vprod;                            \
    __syncthreads();                                                         \
  }

  for (int g = 0; g < NG - 1; ++g) DTW_GROUP(g * KBAR, false);
  DTW_GROUP((NG - 1) * KBAR, true);
#undef DTW_GROUP
#undef MICRO

  if (w == NW - 1 && t == 63) out[b] = res;  // R[1023,1023]
}

extern "C" void kernel_launch(void* const* d_in, const int* in_sizes, int n_in,
                              void* d_out, int out_size, void* d_ws, size_t ws_size,
                              hipStream_t stream) {
  const float* a  = (const float*)d_in[0];
  const float* b  = (const float*)d_in[1];
  const float* W1 = (const float*)d_in[2];
  const float* b1 = (const float*)d_in[3];
  const float* W2 = (const float*)d_in[4];
  const float* b2 = (const float*)d_in[5];
  float* out = (float*)d_out;

  size_t per_part = (size_t)2 * BATCH * L * sizeof(float);
  int parts = 1;
  if (ws_size >= 4 * per_part) parts = 4;
  else if (ws_size >= 2 * per_part) parts = 2;

  float* ap = (float*)d_ws;                    // parts x [BATCH, L]
  float* bp = ap + (size_t)parts * BATCH * L;  // parts x [BATCH, L]

  proj_kernel<<<128 * parts, 256, 0, stream>>>(a, b, W1, b1, W2, b2,
                                               ap, bp, L / parts);
  dtw_kernel<<<BATCH, 256, 0, stream>>>(ap, bp, out, parts);
}